// Round 15
// baseline (413.126 us; speedup 1.0000x reference)
//
#include <hip/hip_runtime.h>

#define INFV 1e8f
#define LN2F 0.69314718055994530942f
#define L2EF 1.44269504088896340736f

constexpr int NC = 512;   // DP columns
constexpr int RW = 128;   // rows per wave
constexpr int NW = 4;     // waves per pipe
constexpr int RC = 72;    // ring columns (9 panels of 8)
constexpr int GOFF = 11;  // wave offset in groups (88 steps, R12/R14-proven)
constexpr int NGRP = 105;

// R14 structure with TWO independent batches ("pipes" A/B) interleaved in
// each wave's instruction stream. Rationale: R14 counters show ~2200 cy/group
// of issue vs 6240 cy/group wall with 1 wave/SIMD -- ~4000 cy of unhidden
// chain/latency stall. Two independent DP chains per wave fill each other's
// stall slots at the instruction level. Ring stored as bf16 (halves LDS so
// two 4-wave pipelines fit: 147456 B rings + 12288 B mailboxes + flags =
// 159776 <= 163840). Mailboxes, lane handoff, and all DP state remain f32;
// only e^{-D} staging and the R values passing through the ring are rounded
// (bf16 e^{-D}: R err ~0.06; R out: +-1 ulp ~ +-1.0 at R~500; thr 10.16).
static __device__ __forceinline__ float wave_shr1(float v, float old) {
    // lanes 1..63 <- lane-1's v; lane 0 keeps `old` (bound_ctrl=false)
    return __int_as_float(__builtin_amdgcn_update_dpp(
        __float_as_int(old), __float_as_int(v), 0x138, 0xF, 0xF, false));
}
static __device__ __forceinline__ unsigned bf16rn(float x) {  // f32 -> bf16 (RNE)
    const unsigned t = __float_as_uint(x);
    return (t + 0x7FFFu + ((t >> 16) & 1u)) >> 16;
}
static __device__ __forceinline__ float bf16lo(unsigned v) { return __uint_as_float(v << 16); }
static __device__ __forceinline__ float bf16hi(unsigned v) { return __uint_as_float(v & 0xFFFF0000u); }

__global__ __launch_bounds__(256, 1) void sdtw10(const float* __restrict__ D,
                                                 float* __restrict__ O, int B) {
    __shared__ unsigned short ring[2 * NW * RC * RW];  // 147456 B, bf16
    __shared__ float mbox[2][3 * NC];                  // 12288 B, f32
    __shared__ int pflag[2][4];

    const int tid = threadIdx.x;
    const int w = tid >> 6, l = tid & 63;

    if (tid < 8) pflag[tid >> 2][tid & 3] = 0;
    __syncthreads();  // once; no barriers in the loop

    const int bA = blockIdx.x * 2;
    const int bB = min(bA + 1, B - 1);  // odd-B tail: duplicate work, same output
    const float* __restrict__ DgA = D + (size_t)bA * NC * 512 + (size_t)w * RW * NC;
    const float* __restrict__ DgB = D + (size_t)bB * NC * 512 + (size_t)w * RW * NC;
    float* __restrict__ OgA = O + (size_t)bA * NC * 512 + (size_t)w * RW * NC;
    float* __restrict__ OgB = O + (size_t)bB * NC * 512 + (size_t)w * RW * NC;

    unsigned* ringU = (unsigned*)ring;
    const int sbA = (0 * NW + w) * RC * RW;  // short-index ring base, pipe A
    const int sbB = (1 * NW + w) * RC * RW;
    const int uA = sbA >> 1, uB = sbB >> 1;  // u32-index bases

    float4 stA[4], stB[4];  // staged D panels (f32 from global)

    auto panel_load = [&](const float* __restrict__ Dg, float4 (&st)[4], int p) {
#pragma unroll
        for (int k = 0; k < 4; ++k) {
            const int f = k * 64 + l, y = f >> 1, q = f & 1;
            st[k] = *(const float4*)(Dg + (size_t)y * NC + p * 8 + q * 4);
        }
    };
    auto panel_write = [&](const float4 (&st)[4], int sb, int p) {  // e^{-D} as bf16
#pragma unroll
        for (int k = 0; k < 4; ++k) {
            const int f = k * 64 + l, y = f >> 1, q = f & 1;
            const int u0 = p * 8 + q * 4;
#pragma unroll
            for (int j = 0; j < 4; ++j) {
                const int u = u0 + j;
                ring[sb + (u % RC) * RW + (y ^ (u & 30))] =
                    (unsigned short)bf16rn(__expf(-((const float*)&st[k])[j]));
            }
        }
    };
    auto panel_flush = [&](float* __restrict__ Og, int sb, int p) {  // R -> global f32
#pragma unroll
        for (int k = 0; k < 4; ++k) {
            const int f = k * 64 + l, y = f >> 1, q = f & 1;
            const int u0 = p * 8 + q * 4;
            float4 v;
#pragma unroll
            for (int j = 0; j < 4; ++j) {
                const int u = u0 + j;
                ((float*)&v)[j] = __uint_as_float(
                    ((unsigned)ring[sb + (u % RC) * RW + (y ^ (u & 30))]) << 16);
            }
            *(float4*)(Og + (size_t)y * NC + u0) = v;
        }
    };

    for (int p = 0; p < 9; ++p) {
        panel_load(DgA, stA, p); panel_write(stA, sbA, p);
        panel_load(DgB, stB, p); panel_write(stB, sbB, p);
    }
    panel_load(DgA, stA, 9);
    panel_load(DgB, stB, 9);

    // DP state per pipe (all f32; R14 semantics)
    float pA0 = 0.f, pA1 = 0.f, hA = 0.f, EA = 0.f, vabA = 0.f;
    float pB0 = 0.f, pB1 = 0.f, hB = 0.f, EB = 0.f, vabB = 0.f;
    float bpA = (w == 0 && l == 0) ? 0.f : INFV, bpB = bpA;
    float roA = INFV, roB = INFV;
    float caA = INFV, caB = INFV;

    for (int g = 0; g < NGRP; ++g) {
        const int h = g - GOFF * w;
        if (h < 0 || h > 71) continue;
        const int tb = 8 * h;

        // ---- consumer handshake (both pipes share one producer wave) ----
        float mgA[8], mgB[8];
        if (w > 0 && h <= 63) {
            const int need = tb + 8;
            int guard = 0;
            while ((__hip_atomic_load(&pflag[0][w - 1], __ATOMIC_ACQUIRE,
                                      __HIP_MEMORY_SCOPE_WORKGROUP) < need ||
                    __hip_atomic_load(&pflag[1][w - 1], __ATOMIC_ACQUIRE,
                                      __HIP_MEMORY_SCOPE_WORKGROUP) < need) &&
                   ++guard < (1 << 24)) {}
            const float4 a0 = *(const float4*)&mbox[0][(w - 1) * NC + tb];
            const float4 a1 = *(const float4*)&mbox[0][(w - 1) * NC + tb + 4];
            const float4 b0 = *(const float4*)&mbox[1][(w - 1) * NC + tb];
            const float4 b1 = *(const float4*)&mbox[1][(w - 1) * NC + tb + 4];
            mgA[0] = a0.x; mgA[1] = a0.y; mgA[2] = a0.z; mgA[3] = a0.w;
            mgA[4] = a1.x; mgA[5] = a1.y; mgA[6] = a1.z; mgA[7] = a1.w;
            mgB[0] = b0.x; mgB[1] = b0.y; mgB[2] = b0.z; mgB[3] = b0.w;
            mgB[4] = b1.x; mgB[5] = b1.y; mgB[6] = b1.z; mgB[7] = b1.w;
        } else {
#pragma unroll
            for (int j = 0; j < 8; ++j) { mgA[j] = INFV; mgB[j] = INFV; }
        }

        // ---- group start: pd pre-reads (bf16 row-pairs, one u32 each) ----
        int ad[8];
        unsigned puA[8], puB[8];
#pragma unroll
        for (int ph = 0; ph < 8; ++ph) {
            const int c = tb + ph - l;
            const int cs = min(max(c, 0), NC - 1);
            ad[ph] = (cs % RC) * 64 + (l ^ ((cs >> 1) & 15));
            puA[ph] = ringU[uA + ad[ph]];
            puB[ph] = ringU[uB + ad[ph]];
        }

        // ---- 8 phases: two independent chains interleaved, zero LDS ----
        unsigned pkA[8], pkB[8];
        float mbA[8], mbB[8];
#pragma unroll
        for (int ph = 0; ph < 8; ++ph) {
            const int u = tb + ph - l;
            const bool valid = (u >= 0) && (u < NC);
            {  // pipe A
                const float bnd = (w == 0) ? INFV : mgA[ph];
                const float up = wave_shr1(roA, bnd);
                const float dl = bpA; bpA = up;
                if (valid) {
                    float dab;
                    if (u == 0) { EA = (w == 0 && l == 0) ? 0.f : floorf(up * L2EF) + 10.f;
                                  dab = __expf(fmaf(EA, LN2F, -dl)); }
                    else dab = vabA;
                    const float vb = __expf(fmaf(EA, LN2F, -up));
                    const float s0 = (dab + vb) + pA0;
                    const float c0 = bf16lo(puA[ph]) * s0;
                    const float s1 = hA + c0;
                    const float c1 = bf16hi(puA[ph]) * s1;
                    const float o0 = fmaf(EA, LN2F, -__logf(c0));
                    const float o1 = fmaf(EA, LN2F, -__logf(c1));
                    pkA[ph] = bf16rn(o0) | (bf16rn(o1) << 16);
                    pA0 = c0; pA1 = c1; hA = c0 + c1; vabA = vb; roA = o1;
                    mbA[ph] = o1;
                } else { mbA[ph] = INFV; }
            }
            {  // pipe B
                const float bnd = (w == 0) ? INFV : mgB[ph];
                const float up = wave_shr1(roB, bnd);
                const float dl = bpB; bpB = up;
                if (valid) {
                    float dab;
                    if (u == 0) { EB = (w == 0 && l == 0) ? 0.f : floorf(up * L2EF) + 10.f;
                                  dab = __expf(fmaf(EB, LN2F, -dl)); }
                    else dab = vabB;
                    const float vb = __expf(fmaf(EB, LN2F, -up));
                    const float s0 = (dab + vb) + pB0;
                    const float c0 = bf16lo(puB[ph]) * s0;
                    const float s1 = hB + c0;
                    const float c1 = bf16hi(puB[ph]) * s1;
                    const float o0 = fmaf(EB, LN2F, -__logf(c0));
                    const float o1 = fmaf(EB, LN2F, -__logf(c1));
                    pkB[ph] = bf16rn(o0) | (bf16rn(o1) << 16);
                    pB0 = c0; pB1 = c1; hB = c0 + c1; vabB = vb; roB = o1;
                    mbB[ph] = o1;
                } else { mbB[ph] = INFV; }
            }
            if (ph == 7) {  // renorm both pipes (R14 formula)
                const int exA = (int)((__float_as_uint(pA0) >> 23) & 0xffu);
                if (exA != 0) {
                    const int sh = 137 - exA;
                    const float f = __uint_as_float((unsigned)(sh + 127) << 23);
                    EA += (float)sh; pA0 *= f; pA1 *= f; hA *= f; vabA *= f;
                }
                const int exB = (int)((__float_as_uint(pB0) >> 23) & 0xffu);
                if (exB != 0) {
                    const int sh = 137 - exB;
                    const float f = __uint_as_float((unsigned)(sh + 127) << 23);
                    EB += (float)sh; pB0 *= f; pB1 *= f; hB *= f; vabB *= f;
                }
            }
        }

        // ---- group end: batched ring writes (R bf16-pairs, in-place) ----
#pragma unroll
        for (int ph = 0; ph < 8; ++ph) {
            const int u = tb + ph - l;
            if (u >= 0 && u < NC) {
                ringU[uA + ad[ph]] = pkA[ph];
                ringU[uB + ad[ph]] = pkB[ph];
            }
        }

        // ---- mailbox writes + publish (producer; f32, R14-identical) ----
        if (w < 3) {
            if (h >= 8 && l == 63) {
                *(float4*)&mbox[0][w * NC + tb - 64] = make_float4(caA, mbA[0], mbA[1], mbA[2]);
                *(float4*)&mbox[0][w * NC + tb - 60] = make_float4(mbA[3], mbA[4], mbA[5], mbA[6]);
                *(float4*)&mbox[1][w * NC + tb - 64] = make_float4(caB, mbB[0], mbB[1], mbB[2]);
                *(float4*)&mbox[1][w * NC + tb - 60] = make_float4(mbB[3], mbB[4], mbB[5], mbB[6]);
            }
            caA = mbA[7]; caB = mbB[7];
            if (h >= 8 && l == 0) {
                __hip_atomic_store(&pflag[0][w], tb - 56, __ATOMIC_RELEASE,
                                   __HIP_MEMORY_SCOPE_WORKGROUP);
                __hip_atomic_store(&pflag[1][w], tb - 56, __ATOMIC_RELEASE,
                                   __HIP_MEMORY_SCOPE_WORKGROUP);
            }
        }

        // ---- panel events (private rings; R14-identical pipeline) ----
        if (h >= 8) {
            panel_flush(OgA, sbA, h - 8);
            panel_flush(OgB, sbB, h - 8);
            if (h + 1 < 64) {
                panel_write(stA, sbA, h + 1);
                panel_write(stB, sbB, h + 1);
                if (h + 2 < 64) {
                    panel_load(DgA, stA, h + 2);
                    panel_load(DgB, stB, h + 2);
                }
            }
        }
    }
}

extern "C" void kernel_launch(void* const* d_in, const int* in_sizes, int n_in,
                              void* d_out, int out_size, void* d_ws, size_t ws_size,
                              hipStream_t stream) {
    const float* D = (const float*)d_in[0];
    float* out = (float*)d_out;
    const int B = in_sizes[0] / (512 * 512);
    sdtw10<<<(B + 1) / 2, 256, 0, stream>>>(D, out, B);
}

// Round 18
// 276.082 us; speedup vs baseline: 1.4964x; 1.4964x over previous
//
#include <hip/hip_runtime.h>

#define INFV 1e8f
#define LN2F 0.69314718055994530942f
#define L2EF 1.44269504088896340736f

constexpr int NC = 512;   // DP columns
constexpr int RW = 64;    // rows per wave (1 row per lane)
constexpr int NW = 8;     // waves per block -> 2 waves per SIMD
constexpr int RC = 72;    // ring columns (9 panels of 8)
constexpr int GOFF = 9;   // wave offset in groups (72 steps; 1-group slack)
constexpr int NGRP = 72 + 7 * GOFF;  // 135

// R14's proven structure and math (log-domain lane/wave interface, per-lane
// scale E, group-batched LDS, flag handshake, in-place e^{-D}->R ring) at
// NW=8 / 1 row/lane. Rationale: R14 shows ~65% exposed stall with 4 waves
// landing 1-per-SIMD (no intra-SIMD overlap); 8 waves give 2/SIMD so each
// wave's lgkm waits and transcendental latency are hidden by its SIMD-mate
// (R13->R12 proved wave-count dominates step-count). Design invariant from
// R3/R4/R16/R17: the cross-lane interface stays LOG-DOMAIN (scale-free);
// only intra-lane state is P-domain with private E.
static __device__ __forceinline__ float wave_shr1(float v, float old) {
    // lanes 1..63 <- lane-1's v; lane 0 keeps `old` (bound_ctrl=false)
    return __int_as_float(__builtin_amdgcn_update_dpp(
        __float_as_int(old), __float_as_int(v), 0x138, 0xF, 0xF, false));
}

__global__ __launch_bounds__(512, 1) void sdtw13(const float* __restrict__ D,
                                                 float* __restrict__ O) {
    __shared__ __align__(16) float ring[NW * RC * RW];  // 147456 B
    __shared__ __align__(16) float mbox[7 * NC];        // 14336 B (log R)
    __shared__ int pflag[8];                            // 161824 B total

    const int tid = threadIdx.x;
    const int w = tid >> 6, l = tid & 63;
    const int b = blockIdx.x;

    if (tid < 8) pflag[tid] = 0;
    __syncthreads();  // once; no barriers in the loop

    const float* __restrict__ Dg = D + (size_t)b * NC * 512 + (size_t)w * RW * NC;
    float* __restrict__ Og = O + (size_t)b * NC * 512 + (size_t)w * RW * NC;
    float* __restrict__ rg = ring + w * RC * RW;

    // panel helpers: 64 rows x 8 cols = 128 float4; f = k*64+l, y=f>>1, q=f&1
    // (lane pairs share a row -> coalesced global; ring salt (u&62) -> panel
    // writes 2-way on banks (free, m136), compute reads a lane permutation).
    float4 st[2];
    auto panel_load = [&](int p) {
#pragma unroll
        for (int k = 0; k < 2; ++k) {
            const int f = k * 64 + l, y = f >> 1, q = f & 1;
            st[k] = *(const float4*)(Dg + (size_t)y * NC + p * 8 + q * 4);
        }
    };
    auto panel_write = [&](int p) {  // stores e^{-D} (true scale)
#pragma unroll
        for (int k = 0; k < 2; ++k) {
            const int f = k * 64 + l, y = f >> 1, q = f & 1;
            const int ub = p * 8 + q * 4;
#pragma unroll
            for (int j = 0; j < 4; ++j) {
                const int u = ub + j;
                rg[(u % RC) * RW + (y ^ (u & 62))] = __expf(-((const float*)&st[k])[j]);
            }
        }
    };
    auto panel_flush = [&](int p) {  // ring (R values) -> global
#pragma unroll
        for (int k = 0; k < 2; ++k) {
            const int f = k * 64 + l, y = f >> 1, q = f & 1;
            const int ub = p * 8 + q * 4;
            float4 v;
#pragma unroll
            for (int j = 0; j < 4; ++j) {
                const int u = ub + j;
                ((float*)&v)[j] = rg[(u % RC) * RW + (y ^ (u & 62))];
            }
            *(float4*)(Og + (size_t)y * NC + ub) = v;
        }
    };

    for (int p = 0; p < 9; ++p) { panel_load(p); panel_write(p); }
    panel_load(9);

    float prevP = 0.f;                  // stored P[row l, u-1] = e^{-R} * 2^E
    float E = 0.f;                      // private per-lane scale
    float bp_r = (w == 0 && l == 0) ? 0.f : INFV;  // log R[l-1, u-1]
    float r_out = INFV;                 // log R[l, u] for lane l+1
    float vab_prev = 0.f;               // cached P(R[l-1, u-1]) at E
    float carry = INFV;                 // lane63 o carried one group (log)

    for (int g = 0; g < NGRP; ++g) {
        const int h = g - GOFF * w;     // wave-local group index
        if (h < 0 || h > 71) continue;
        const int tb = 8 * h;

        // ---- group start: consumer handshake + mailbox batch read ----
        float mg[8];
        if (w > 0 && h <= 63) {
            const int need = tb + 8;  // cols tb..tb+7
            int guard = 0;
            while (__hip_atomic_load(&pflag[w - 1], __ATOMIC_ACQUIRE,
                                     __HIP_MEMORY_SCOPE_WORKGROUP) < need &&
                   ++guard < (1 << 24)) {}
            const float4 m0 = *(const float4*)&mbox[(w - 1) * NC + tb];
            const float4 m1 = *(const float4*)&mbox[(w - 1) * NC + tb + 4];
            mg[0] = m0.x; mg[1] = m0.y; mg[2] = m0.z; mg[3] = m0.w;
            mg[4] = m1.x; mg[5] = m1.y; mg[6] = m1.z; mg[7] = m1.w;
        } else {
#pragma unroll
            for (int j = 0; j < 8; ++j) mg[j] = INFV;  // row -1 boundary
        }

        // ---- group start: pd pre-reads (8x b32, one lgkm region) ----
        int ad[8];
        float pdv[8];
#pragma unroll
        for (int ph = 0; ph < 8; ++ph) {
            const int c = tb + ph - l;           // col u for this phase
            const int cs = min(max(c, 0), NC - 1);
            ad[ph] = (cs % RC) * RW + (l ^ (cs & 62));
            pdv[ph] = rg[ad[ph]];
        }

        // ---- 8 phases: 1 cell each (R14 math, single row) ----
        float obuf[8], mbuf[8];
#pragma unroll
        for (int ph = 0; ph < 8; ++ph) {
            const int u = tb + ph - l;
            const bool valid = (u >= 0) && (u < NC);
            const float bnd = (w == 0) ? INFV : mg[ph];
            const float up_r = wave_shr1(r_out, bnd);  // log R[l-1, u]
            const float dab_log = bp_r;                // log R[l-1, u-1]
            bp_r = up_r;
            if (valid) {
                float dab;
                if (u == 0) {  // cold start: adopt scale, pin boundary ~2^10
                    E = (w == 0 && l == 0) ? 0.f : floorf(up_r * L2EF) + 10.f;
                    dab = __expf(fmaf(E, LN2F, -dab_log));
                } else {
                    dab = vab_prev;
                }
                const float vab = __expf(fmaf(E, LN2F, -up_r));  // chain exp
                const float s = (dab + vab) + prevP;
                const float c = pdv[ph] * s;
                const float o = fmaf(E, LN2F, -__logf(c));
                obuf[ph] = o;
                prevP = c; vab_prev = vab; r_out = o;
                mbuf[ph] = o;
            } else {
                mbuf[ph] = INFV;
            }
        }

        // ---- group end: batched ring writes (R replaces e^{-D}) ----
#pragma unroll
        for (int ph = 0; ph < 8; ++ph) {
            const int u = tb + ph - l;
            if (u >= 0 && u < NC) rg[ad[ph]] = obuf[ph];
        }

        // ---- group end: mailbox write + publish (log domain, R14-proven) ----
        if (w < 7) {
            if (h >= 8 && l == 63) {  // chunk h-8 = cols tb-64..tb-57
                *(float4*)&mbox[w * NC + tb - 64] =
                    make_float4(carry, mbuf[0], mbuf[1], mbuf[2]);
                *(float4*)&mbox[w * NC + tb - 60] =
                    make_float4(mbuf[3], mbuf[4], mbuf[5], mbuf[6]);
            }
            carry = mbuf[7];
            if (h >= 8 && l == 0) {
                __hip_atomic_store(&pflag[w], tb - 56, __ATOMIC_RELEASE,
                                   __HIP_MEMORY_SCOPE_WORKGROUP);
            }
        }

        // ---- group end: renorm (pin stored prevP ~2^10; log r_out immune) ----
        {
            const int ex = (int)((__float_as_uint(prevP) >> 23) & 0xffu);
            if (ex != 0) {  // skip not-yet-started lanes
                const int sh = 137 - ex;
                const float f = __uint_as_float((unsigned)(sh + 127) << 23);
                E += (float)sh;
                prevP *= f; vab_prev *= f;
            }
        }

        // ---- group end: panel event (private ring; ordering as R14) ----
        if (h >= 8) {
            panel_flush(h - 8);
            if (h + 1 < 64) {
                panel_write(h + 1);
                if (h + 2 < 64) panel_load(h + 2);
            }
        }
    }
}

extern "C" void kernel_launch(void* const* d_in, const int* in_sizes, int n_in,
                              void* d_out, int out_size, void* d_ws, size_t ws_size,
                              hipStream_t stream) {
    const float* D = (const float*)d_in[0];
    float* out = (float*)d_out;
    const int B = in_sizes[0] / (512 * 512);
    sdtw13<<<B, 512, 0, stream>>>(D, out);
}

// Round 19
// 176.145 us; speedup vs baseline: 2.3454x; 1.5674x over previous
//
#include <hip/hip_runtime.h>

#define INFV 1e8f
#define LN2F 0.69314718055994530942f
#define L2EF 1.44269504088896340736f

constexpr int NC = 512;   // DP columns
constexpr int RW = 128;   // rows per wave
constexpr int NW = 4;     // waves per block
constexpr int RC = 72;    // ring columns (9 panels of 8)
constexpr int GOFF = 10;  // wave offset in groups (80 steps; 1-group slack)
constexpr int NGRP = 72 + 3 * GOFF;  // 102

// R14 host (4 waves/batch, 2 rows/lane, private in-place LDS ring, group-
// batched LDS, log-domain lane/wave interface, per-lane scale E) with an
// instruction diet:
//  - ring salt REMOVED: [slot][y] layout is already <=2-way on banks for
//    both access patterns (compute b64: bank 2l&31; panel b32: bank y&31;
//    2-way = free per m136). R18's 9.5M conflicts came from its salt.
//  - FAST PATH for interior groups (8<=h<=63): u in [1,511] for all lanes
//    and phases -> no clamps, no validity predicates, no u==0 cold-start,
//    no bp_r upkeep; slot via one v%RC + add/wrap-select instead of 8
//    magic-muls; panel helpers use one (8p)%RC per call, not 16.
//  - GOFF 11->10 (publish cnt at producer group h+9 = 8h+16 >= need 8h+8).
// Slow path (h<8, h>63) = R14 body verbatim. Math/protocol untouched.
static __device__ __forceinline__ float wave_shr1(float v, float old) {
    // lanes 1..63 <- lane-1's v; lane 0 keeps `old` (bound_ctrl=false)
    return __int_as_float(__builtin_amdgcn_update_dpp(
        __float_as_int(old), __float_as_int(v), 0x138, 0xF, 0xF, false));
}

__global__ __launch_bounds__(256, 1) void sdtw14(const float* __restrict__ D,
                                                 float* __restrict__ O) {
    __shared__ __align__(16) float ring[NW * RC * RW];  // 147456 B
    __shared__ __align__(16) float mbox[3 * NC];        // 6144 B (log R)
    __shared__ int pflag[4];

    const int tid = threadIdx.x;
    const int w = tid >> 6, l = tid & 63;
    const int b = blockIdx.x;

    if (tid < 4) pflag[tid] = 0;
    __syncthreads();  // once; no barriers in the loop

    const float* __restrict__ Dg = D + (size_t)b * NC * 512 + (size_t)w * RW * NC;
    float* __restrict__ Og = O + (size_t)b * NC * 512 + (size_t)w * RW * NC;
    float* __restrict__ rg = ring + w * RC * RW;

    // panel helpers: 128 rows x 8 cols; f = k*64+l, y = f>>1, q = f&1.
    // Panel p occupies slots spb..spb+7, spb = (8p)%72 in {0,8,...,64}.
    float4 st[4];
    auto panel_load = [&](int p) {
#pragma unroll
        for (int k = 0; k < 4; ++k) {
            const int f = k * 64 + l, y = f >> 1, q = f & 1;
            st[k] = *(const float4*)(Dg + (size_t)y * NC + p * 8 + q * 4);
        }
    };
    auto panel_write = [&](int p) {  // stores e^{-D} (true scale)
        const int spb = (p * 8) % RC;  // one magic-mul per call
#pragma unroll
        for (int k = 0; k < 4; ++k) {
            const int f = k * 64 + l, y = f >> 1, q = f & 1;
#pragma unroll
            for (int j = 0; j < 4; ++j)
                rg[(spb + q * 4 + j) * RW + y] = __expf(-((const float*)&st[k])[j]);
        }
    };
    auto panel_flush = [&](int p) {  // ring (R values) -> global
        const int spb = (p * 8) % RC;
#pragma unroll
        for (int k = 0; k < 4; ++k) {
            const int f = k * 64 + l, y = f >> 1, q = f & 1;
            float4 v;
#pragma unroll
            for (int j = 0; j < 4; ++j)
                ((float*)&v)[j] = rg[(spb + q * 4 + j) * RW + y];
            *(float4*)(Og + (size_t)y * NC + p * 8 + q * 4) = v;
        }
    };

    for (int p = 0; p < 9; ++p) { panel_load(p); panel_write(p); }
    panel_load(9);

    const int y0 = 2 * l;
    float prevP0 = 0.f, prevP1 = 0.f;  // stored P[row, u-1] = e^{-R} * 2^E
    float h01 = 0.f;                   // prevP0 + prevP1
    float E = 0.f;                     // private per-lane scale
    float bp_r = (w == 0 && l == 0) ? 0.f : INFV;  // log R[above, u-1] (slow path)
    float r_out = INFV;                // log R[y0+1, u] for next lane
    float vab_prev = 0.f;              // cached P(R[above, u-1]) at E
    float carry = INFV;                // lane63 o1 carried one group

    for (int g = 0; g < NGRP; ++g) {
        const int h = g - GOFF * w;
        if (h < 0 || h > 71) continue;
        const int tb = 8 * h;

        // ---- group start: consumer handshake + mailbox batch read ----
        float mg[8];
        if (w > 0 && h <= 63) {
            const int need = tb + 8;
            int guard = 0;
            while (__hip_atomic_load(&pflag[w - 1], __ATOMIC_ACQUIRE,
                                     __HIP_MEMORY_SCOPE_WORKGROUP) < need &&
                   ++guard < (1 << 24)) {}
            const float4 m0 = *(const float4*)&mbox[(w - 1) * NC + tb];
            const float4 m1 = *(const float4*)&mbox[(w - 1) * NC + tb + 4];
            mg[0] = m0.x; mg[1] = m0.y; mg[2] = m0.z; mg[3] = m0.w;
            mg[4] = m1.x; mg[5] = m1.y; mg[6] = m1.z; mg[7] = m1.w;
        } else {
#pragma unroll
            for (int j = 0; j < 8; ++j) mg[j] = INFV;
        }

        float mbuf[8];

        if (h >= 8 && h <= 63) {
            // ================= FAST PATH (interior; all lanes valid) =======
            const int v = tb - l;        // in [1, 504]
            const int sb = v % RC;       // one magic-mul
            const int base = sb * RW + y0;
            int ad[8];
            float2 pdv[8];
#pragma unroll
            for (int ph = 0; ph < 8; ++ph) {
                int a = base + ph * RW;
                if (sb + ph >= RC) a -= RC * RW;  // single wrap possible
                ad[ph] = a;
                pdv[ph] = *(const float2*)&rg[a];
            }
            float2 obuf[8];
#pragma unroll
            for (int ph = 0; ph < 8; ++ph) {
                const float bnd = (w == 0) ? INFV : mg[ph];
                const float up_r = wave_shr1(r_out, bnd);        // log R[y0-1,u]
                const float vab = __expf(fmaf(E, LN2F, -up_r));  // chain exp
                const float s0 = (vab_prev + vab) + prevP0;      // dab == vab_prev
                const float c0 = pdv[ph].x * s0;
                const float s1 = h01 + c0;
                const float c1 = pdv[ph].y * s1;
                const float o0 = fmaf(E, LN2F, -__logf(c0));
                const float o1 = fmaf(E, LN2F, -__logf(c1));
                obuf[ph] = make_float2(o0, o1);
                prevP0 = c0; prevP1 = c1; h01 = c0 + c1;
                vab_prev = vab; r_out = o1; mbuf[ph] = o1;
            }
#pragma unroll
            for (int ph = 0; ph < 8; ++ph) *(float2*)&rg[ad[ph]] = obuf[ph];
        } else {
            // ================= SLOW PATH (boundary; R14 verbatim) ==========
            int ad[8];
            float2 pdv[8];
#pragma unroll
            for (int ph = 0; ph < 8; ++ph) {
                const int c = tb + ph - l;
                const int cs = min(max(c, 0), NC - 1);
                ad[ph] = (cs % RC) * RW + y0;
                pdv[ph] = *(const float2*)&rg[ad[ph]];
            }
            float2 obuf[8];
#pragma unroll
            for (int ph = 0; ph < 8; ++ph) {
                const int u = tb + ph - l;
                const bool valid = (u >= 0) && (u < NC);
                const float bnd = (w == 0) ? INFV : mg[ph];
                const float up_r = wave_shr1(r_out, bnd);
                const float dab_log = bp_r;
                bp_r = up_r;
                if (valid) {
                    float dab;
                    if (u == 0) {  // cold start: adopt scale, pin boundary ~2^10
                        E = (w == 0 && l == 0) ? 0.f : floorf(up_r * L2EF) + 10.f;
                        dab = __expf(fmaf(E, LN2F, -dab_log));
                    } else {
                        dab = vab_prev;
                    }
                    const float vab = __expf(fmaf(E, LN2F, -up_r));
                    const float s0 = (dab + vab) + prevP0;
                    const float c0 = pdv[ph].x * s0;
                    const float s1 = h01 + c0;
                    const float c1 = pdv[ph].y * s1;
                    const float o0 = fmaf(E, LN2F, -__logf(c0));
                    const float o1 = fmaf(E, LN2F, -__logf(c1));
                    obuf[ph] = make_float2(o0, o1);
                    prevP0 = c0; prevP1 = c1; h01 = c0 + c1;
                    vab_prev = vab; r_out = o1; mbuf[ph] = o1;
                } else {
                    mbuf[ph] = INFV;
                }
            }
#pragma unroll
            for (int ph = 0; ph < 8; ++ph) {
                const int u = tb + ph - l;
                if (u >= 0 && u < NC) *(float2*)&rg[ad[ph]] = obuf[ph];
            }
        }

        // ---- group end: mailbox write + publish (log domain) ----
        if (w < 3) {
            if (h >= 8 && l == 63) {  // chunk h-8 = cols tb-64..tb-57
                *(float4*)&mbox[w * NC + tb - 64] =
                    make_float4(carry, mbuf[0], mbuf[1], mbuf[2]);
                *(float4*)&mbox[w * NC + tb - 60] =
                    make_float4(mbuf[3], mbuf[4], mbuf[5], mbuf[6]);
            }
            carry = mbuf[7];
            if (h >= 8 && l == 0) {
                __hip_atomic_store(&pflag[w], tb - 56, __ATOMIC_RELEASE,
                                   __HIP_MEMORY_SCOPE_WORKGROUP);
            }
        }

        // ---- group end: renorm (pin stored prevP0 ~2^10; log r_out immune) --
        {
            const int ex = (int)((__float_as_uint(prevP0) >> 23) & 0xffu);
            if (ex != 0) {
                const int sh = 137 - ex;
                const float f = __uint_as_float((unsigned)(sh + 127) << 23);
                E += (float)sh;
                prevP0 *= f; prevP1 *= f; h01 *= f; vab_prev *= f;
            }
        }

        // ---- group end: panel event (private ring; R14-proven ordering) ----
        if (h >= 8) {
            panel_flush(h - 8);
            if (h + 1 < 64) {
                panel_write(h + 1);
                if (h + 2 < 64) panel_load(h + 2);
            }
        }
    }
}

extern "C" void kernel_launch(void* const* d_in, const int* in_sizes, int n_in,
                              void* d_out, int out_size, void* d_ws, size_t ws_size,
                              hipStream_t stream) {
    const float* D = (const float*)d_in[0];
    float* out = (float*)d_out;
    const int B = in_sizes[0] / (512 * 512);
    sdtw14<<<B, 256, 0, stream>>>(D, out);
}